// Round 8
// baseline (374.516 us; speedup 1.0000x reference)
//
#include <hip/hip_runtime.h>
#include <math.h>

#define NB   2048
#define NS   512
#define NF   15
#define NH   32
#define NTL  24
#define BPB  8                 // batches per block
#define CHK  32                // steps staged per chunk
#define NCHK (NS/CHK)          // 16
#define LOADS ((BPB*CHK*NF)/256)  // 15 loads per thread per chunk

__global__ __launch_bounds__(256, 1)
void gru_fused(const float* __restrict__ x,
               const float* __restrict__ Wd,  const float* __restrict__ bd,
               const float* __restrict__ Wih, const float* __restrict__ Whh,
               const float* __restrict__ bih, const float* __restrict__ bhh,
               const float* __restrict__ Wo,  const float* __restrict__ bo,
               float* __restrict__ out)
{
    const int tid  = threadIdx.x;
    const int lane = tid & 31;     // hidden index i
    const int grp  = tid >> 5;     // batch within block
    const int gb   = blockIdx.x * BPB + grp;

    __shared__ float Wc[3*NH*NF];          // combined input weights 96x15
    __shared__ float xs[2][BPB*CHK*NF];    // x staging, double buffered

    // cooperative W_comb = W_ih @ W_dense  (96x15)
    for (int idx = tid; idx < 3*NH*NF; idx += 256) {
        const int g = idx / NF, f = idx - g*NF;
        float a = 0.f;
        #pragma unroll
        for (int k = 0; k < NH; ++k) a = fmaf(Wih[g*NH+k], Wd[k*NF+f], a);
        Wc[idx] = a;
    }

    // per-lane recurrent weights: rows i, i+32, i+64 of W_hh
    float Wr[NH], Wz[NH], Wn[NH];
    #pragma unroll
    for (int j = 0; j < NH; ++j) {
        Wr[j] = Whh[(lane       )*NH + j];
        Wz[j] = Whh[(lane +   NH)*NH + j];
        Wn[j] = Whh[(lane + 2*NH)*NH + j];
    }
    // biases: fold b_ih + W_ih@b_dense (+ b_hh for r,z) per lane
    float br = 0.f, bz = 0.f, bnx = 0.f;
    #pragma unroll
    for (int k = 0; k < NH; ++k) {
        br  = fmaf(Wih[(lane       )*NH + k], bd[k], br);
        bz  = fmaf(Wih[(lane +   NH)*NH + k], bd[k], bz);
        bnx = fmaf(Wih[(lane + 2*NH)*NH + k], bd[k], bnx);
    }
    br  += bih[lane]        + bhh[lane];
    bz  += bih[lane +   NH] + bhh[lane +   NH];
    bnx += bih[lane + 2*NH];
    const float bnh = bhh[lane + 2*NH];   // stays inside r*(...)
    const float wo  = Wo[lane];
    const float bo0 = bo[0];

    __syncthreads();   // Wc ready

    float Cr[NF], Cz[NF], Cn[NF];
    #pragma unroll
    for (int f = 0; f < NF; ++f) {
        Cr[f] = Wc[(lane       )*NF + f];
        Cz[f] = Wc[(lane +   NH)*NF + f];
        Cn[f] = Wc[(lane + 2*NH)*NF + f];
    }

    // staging geometry (constant across chunks)
    const float* xblk = x + (size_t)blockIdx.x * BPB * NS * NF;
    int offs[LOADS];
    #pragma unroll
    for (int k = 0; k < LOADS; ++k) {
        const int idx = tid + k*256;
        const int bb  = idx / (CHK*NF);
        const int rem = idx - bb*(CHK*NF);
        offs[k] = bb*NS*NF + rem;
    }
    float st[LOADS];
    #pragma unroll
    for (int k = 0; k < LOADS; ++k) st[k] = xblk[offs[k]];
    #pragma unroll
    for (int k = 0; k < LOADS; ++k) xs[0][tid + k*256] = st[k];
    __syncthreads();   // chunk 0 staged

    float h = 0.f;
    int buf = 0;
    for (int c = 0; c < NCHK; ++c) {
        // issue next chunk's global loads (hide under compute)
        if (c + 1 < NCHK) {
            #pragma unroll
            for (int k = 0; k < LOADS; ++k)
                st[k] = xblk[offs[k] + (c+1)*CHK*NF];
        }
        const float* xc = &xs[buf][grp*CHK*NF];
        #pragma unroll 2
        for (int s = 0; s < CHK; ++s) {
            float xv[NF];
            #pragma unroll
            for (int f = 0; f < NF; ++f) xv[f] = xc[s*NF + f];

            // broadcast all 32 h values within the 32-lane group.
            // ds_swizzle BitMode offset = (xor<<10)|(or<<5)|and; and=0,or=J
            // -> every lane reads lane J of its 32-lane half. Offset must be
            // an integer constant expression, hence the macro expansion.
            const int hi = __float_as_int(h);
            float hb[NH];
            #define BC(J)  hb[(J)] = __int_as_float(__builtin_amdgcn_ds_swizzle(hi, ((J) << 5)))
            #define BC4(J) BC(J); BC((J)+1); BC((J)+2); BC((J)+3)
            BC4(0); BC4(4); BC4(8); BC4(12); BC4(16); BC4(20); BC4(24); BC4(28);
            #undef BC4
            #undef BC

            float dr = 0.f, dz = 0.f, dn = 0.f;
            #pragma unroll
            for (int j = 0; j < NH; ++j) {
                dr = fmaf(Wr[j], hb[j], dr);
                dz = fmaf(Wz[j], hb[j], dz);
                dn = fmaf(Wn[j], hb[j], dn);
            }
            float gr = br, gz = bz, gn = bnx;
            #pragma unroll
            for (int f = 0; f < NF; ++f) {
                gr = fmaf(Cr[f], xv[f], gr);
                gz = fmaf(Cz[f], xv[f], gz);
                gn = fmaf(Cn[f], xv[f], gn);
            }
            const float ar = gr + dr;
            const float az = gz + dz;
            const float r  = __builtin_amdgcn_rcpf(1.f + __expf(-ar));
            const float z  = __builtin_amdgcn_rcpf(1.f + __expf(-az));
            const float tt = gn + r*(dn + bnh);
            const float e  = __expf(-2.f*fabsf(tt));
            float th = (1.f - e) * __builtin_amdgcn_rcpf(1.f + e);
            th = copysignf(th, tt);
            h = z*(h - th) + th;        // (1-z)*tanh + z*h

            const int sg = c*CHK + s;
            if (sg >= NS - NTL) {
                float p = wo * h;
                #pragma unroll
                for (int off = 16; off; off >>= 1) p += __shfl_xor(p, off, 32);
                if (lane == 0) out[gb*NTL + sg - (NS - NTL)] = p + bo0;
            }
        }
        if (c + 1 < NCHK) {
            __syncthreads();
            #pragma unroll
            for (int k = 0; k < LOADS; ++k) xs[buf ^ 1][tid + k*256] = st[k];
            __syncthreads();
            buf ^= 1;
        }
    }
}

extern "C" void kernel_launch(void* const* d_in, const int* in_sizes, int n_in,
                              void* d_out, int out_size, void* d_ws, size_t ws_size,
                              hipStream_t stream) {
    const float* x   = (const float*)d_in[0];
    const float* Wd  = (const float*)d_in[1];
    const float* bd  = (const float*)d_in[2];
    const float* Wih = (const float*)d_in[3];
    const float* Whh = (const float*)d_in[4];
    const float* bih = (const float*)d_in[5];
    const float* bhh = (const float*)d_in[6];
    const float* Wo  = (const float*)d_in[7];
    const float* bo  = (const float*)d_in[8];
    float* out = (float*)d_out;

    dim3 grid(NB / BPB), block(256);
    hipLaunchKernelGGL(gru_fused, grid, block, 0, stream,
                       x, Wd, bd, Wih, Whh, bih, bhh, Wo, bo, out);
}